// Round 3
// baseline (1194.646 us; speedup 1.0000x reference)
//
#include <hip/hip_runtime.h>

#define T_LEN 16384
#define L_BLK 128
#define K_BLK (T_LEN / L_BLK)   // 128 blocks per signal
#define NSEC 6                   // order-5 butter = 3 SOS sections; hp+lp = 6
#define NSTATE (2 * NSEC)        // 12 state vars
#define LOG2_L 7                 // log2(128)
#define NS_TOT 2048              // 32*64 signals

// Static device scratch — no dependence on ws_size. Fully rewritten every call.
__device__ float  g_szs[(size_t)NS_TOT * K_BLK * NSTATE];  // zero-state end states
__device__ float  g_sin[(size_t)NS_TOT * K_BLK * NSTATE];  // true incoming states
__device__ double g_M[NSTATE * NSTATE];                    // A^L_BLK (fp64)

// ---------------------------------------------------------------------------
// Pass 1: per (signal, block) filter from zero state; record final state only.
// ---------------------------------------------------------------------------
__global__ void k_pass1(const float* __restrict__ x, const float* __restrict__ sos,
                        int NS) {
    int gid = blockIdx.x * blockDim.x + threadIdx.x;
    int total = NS * K_BLK;
    if (gid >= total) return;
    int sig = gid / K_BLK;
    int blk = gid % K_BLK;

    float b0[NSEC], b1[NSEC], b2[NSEC], a1[NSEC], a2[NSEC];
#pragma unroll
    for (int i = 0; i < NSEC; ++i) {
        b0[i] = sos[i * 6 + 0];
        b1[i] = sos[i * 6 + 1];
        b2[i] = sos[i * 6 + 2];
        a1[i] = sos[i * 6 + 4];
        a2[i] = sos[i * 6 + 5];
    }
    float w1[NSEC], w2[NSEC];
#pragma unroll
    for (int i = 0; i < NSEC; ++i) { w1[i] = 0.f; w2[i] = 0.f; }

    const float* xp = x + (size_t)sig * T_LEN + (size_t)blk * L_BLK;
#pragma unroll 2
    for (int t = 0; t < L_BLK; t += 4) {
        float4 v = *reinterpret_cast<const float4*>(xp + t);
        float in4[4] = {v.x, v.y, v.z, v.w};
#pragma unroll
        for (int q = 0; q < 4; ++q) {
            float cur = in4[q];
#pragma unroll
            for (int i = 0; i < NSEC; ++i) {
                float y = fmaf(b0[i], cur, w1[i]);
                w1[i] = fmaf(b1[i], cur, fmaf(-a1[i], y, w2[i]));
                w2[i] = fmaf(b2[i], cur, -(a2[i] * y));
                cur = y;
            }
        }
    }
    float* o = g_szs + (size_t)gid * NSTATE;
#pragma unroll
    for (int i = 0; i < NSEC; ++i) { o[2 * i] = w1[i]; o[2 * i + 1] = w2[i]; }
}

// ---------------------------------------------------------------------------
// Build A (one-step state transition, zero input) in fp64; M = A^L_BLK by
// LOG2_L LDS squarings. One block, 256 threads (144 active for matmul).
// ---------------------------------------------------------------------------
__global__ void k_matpow(const float* __restrict__ sos) {
    __shared__ double A[NSTATE * NSTATE];
    int tid = threadIdx.x;

    if (tid < NSTATE) {
        double b0[NSEC], b1[NSEC], b2[NSEC], a1[NSEC], a2[NSEC];
#pragma unroll
        for (int i = 0; i < NSEC; ++i) {
            b0[i] = (double)sos[i * 6 + 0];
            b1[i] = (double)sos[i * 6 + 1];
            b2[i] = (double)sos[i * 6 + 2];
            a1[i] = (double)sos[i * 6 + 4];
            a2[i] = (double)sos[i * 6 + 5];
        }
        double w1[NSEC], w2[NSEC];
#pragma unroll
        for (int i = 0; i < NSEC; ++i) {
            w1[i] = (tid == 2 * i) ? 1.0 : 0.0;
            w2[i] = (tid == 2 * i + 1) ? 1.0 : 0.0;
        }
        double cur = 0.0;   // zero input: propagate unit-state probe one step
#pragma unroll
        for (int i = 0; i < NSEC; ++i) {
            double y = fma(b0[i], cur, w1[i]);
            double nw1 = fma(b1[i], cur, fma(-a1[i], y, w2[i]));
            double nw2 = fma(b2[i], cur, -(a2[i] * y));
            w1[i] = nw1; w2[i] = nw2; cur = y;
        }
#pragma unroll
        for (int i = 0; i < NSEC; ++i) {
            A[(2 * i) * NSTATE + tid]     = w1[i];   // column tid of A
            A[(2 * i + 1) * NSTATE + tid] = w2[i];
        }
    }
    __syncthreads();

    int r = tid / NSTATE, c = tid % NSTATE;
    for (int it = 0; it < LOG2_L; ++it) {
        double v = 0.0;
        if (tid < NSTATE * NSTATE) {
#pragma unroll
            for (int k = 0; k < NSTATE; ++k) v = fma(A[r * NSTATE + k], A[k * NSTATE + c], v);
        }
        __syncthreads();
        if (tid < NSTATE * NSTATE) A[r * NSTATE + c] = v;
        __syncthreads();
    }
    if (tid < NSTATE * NSTATE) g_M[tid] = A[tid];
}

// ---------------------------------------------------------------------------
// Scan (fp64): per-signal serial over blocks: s(k+1) = M*s(k) + szs(k).
// Writes the incoming state of every block (fp32).
// ---------------------------------------------------------------------------
__global__ void k_scan(int NS) {
    __shared__ double Ms[NSTATE * NSTATE];
    for (int i = threadIdx.x; i < NSTATE * NSTATE; i += blockDim.x) Ms[i] = g_M[i];
    __syncthreads();
    int sig = blockIdx.x * blockDim.x + threadIdx.x;
    if (sig >= NS) return;

    double s[NSTATE];
#pragma unroll
    for (int j = 0; j < NSTATE; ++j) s[j] = 0.0;

    for (int blk = 0; blk < K_BLK; ++blk) {
        size_t base = ((size_t)sig * K_BLK + blk) * NSTATE;
#pragma unroll
        for (int j = 0; j < NSTATE; ++j) g_sin[base + j] = (float)s[j];
        double ns[NSTATE];
#pragma unroll
        for (int rr = 0; rr < NSTATE; ++rr) {
            double v = (double)g_szs[base + rr];
#pragma unroll
            for (int k = 0; k < NSTATE; ++k) v = fma(Ms[rr * NSTATE + k], s[k], v);
            ns[rr] = v;
        }
#pragma unroll
        for (int j = 0; j < NSTATE; ++j) s[j] = ns[j];
    }
}

// ---------------------------------------------------------------------------
// Pass 3: per (signal, block) filter seeded with true incoming state; write y.
// ---------------------------------------------------------------------------
__global__ void k_pass3(const float* __restrict__ x, const float* __restrict__ sos,
                        float* __restrict__ y, int NS) {
    int gid = blockIdx.x * blockDim.x + threadIdx.x;
    int total = NS * K_BLK;
    if (gid >= total) return;
    int sig = gid / K_BLK;
    int blk = gid % K_BLK;

    float b0[NSEC], b1[NSEC], b2[NSEC], a1[NSEC], a2[NSEC];
#pragma unroll
    for (int i = 0; i < NSEC; ++i) {
        b0[i] = sos[i * 6 + 0];
        b1[i] = sos[i * 6 + 1];
        b2[i] = sos[i * 6 + 2];
        a1[i] = sos[i * 6 + 4];
        a2[i] = sos[i * 6 + 5];
    }
    const float* st = g_sin + (size_t)gid * NSTATE;
    float w1[NSEC], w2[NSEC];
#pragma unroll
    for (int i = 0; i < NSEC; ++i) { w1[i] = st[2 * i]; w2[i] = st[2 * i + 1]; }

    const float* xp = x + (size_t)sig * T_LEN + (size_t)blk * L_BLK;
    float* yp = y + (size_t)sig * T_LEN + (size_t)blk * L_BLK;
#pragma unroll 2
    for (int t = 0; t < L_BLK; t += 4) {
        float4 v = *reinterpret_cast<const float4*>(xp + t);
        float in4[4] = {v.x, v.y, v.z, v.w};
        float out4[4];
#pragma unroll
        for (int q = 0; q < 4; ++q) {
            float cur = in4[q];
#pragma unroll
            for (int i = 0; i < NSEC; ++i) {
                float yv = fmaf(b0[i], cur, w1[i]);
                w1[i] = fmaf(b1[i], cur, fmaf(-a1[i], yv, w2[i]));
                w2[i] = fmaf(b2[i], cur, -(a2[i] * yv));
                cur = yv;
            }
            out4[q] = cur;
        }
        *reinterpret_cast<float4*>(yp + t) = make_float4(out4[0], out4[1], out4[2], out4[3]);
    }
}

extern "C" void kernel_launch(void* const* d_in, const int* in_sizes, int n_in,
                              void* d_out, int out_size, void* d_ws, size_t ws_size,
                              hipStream_t stream) {
    const float* x   = (const float*)d_in[0];
    const float* sos = (const float*)d_in[1];
    // Insurance: sos has 36 elements, x has millions — swap if order differs.
    if (n_in >= 2 && in_sizes[0] <= 256 && in_sizes[1] > 256) {
        x = (const float*)d_in[1];
        sos = (const float*)d_in[0];
    }
    float* out = (float*)d_out;

    int NS = out_size / T_LEN;      // 2048 signals
    if (NS > NS_TOT) NS = NS_TOT;
    if (NS < 1) NS = 1;

    int nthr = NS * K_BLK;          // 262144
    int blocks = (nthr + 255) / 256;

    k_pass1<<<blocks, 256, 0, stream>>>(x, sos, NS);
    k_matpow<<<1, 256, 0, stream>>>(sos);
    k_scan<<<(NS + 255) / 256, 256, 0, stream>>>(NS);
    k_pass3<<<blocks, 256, 0, stream>>>(x, sos, out, NS);
}

// Round 4
// 157.339 us; speedup vs baseline: 7.5928x; 7.5928x over previous
//
#include <hip/hip_runtime.h>

#define T_LEN 16384
#define L_BLK 128
#define K_BLK (T_LEN / L_BLK)   // 128 blocks per signal = threads per workgroup
#define NSEC 6                   // order-5 butter = 3 SOS sections; hp+lp = 6
#define NSTATE (2 * NSEC)        // 12 state vars
#define NPOW 7                   // M^(2^i), i=0..6  (M = A^128)
#define NS_TOT 2048

// M powers: g_Mp[i] = (A^128)^(2^i), fp32, built in fp64.
__device__ float g_Mp[NPOW * NSTATE * NSTATE];

// ---------------------------------------------------------------------------
// Build A (one-step transition, zero input) in fp64; square 13 times.
// After j squarings A = A0^(2^j); for j=7..13 store as M^(2^(j-7)).
// ---------------------------------------------------------------------------
__global__ void k_matpow(const float* __restrict__ sos) {
    __shared__ double A[NSTATE * NSTATE];
    int tid = threadIdx.x;

    if (tid < NSTATE) {
        double b0[NSEC], b1[NSEC], b2[NSEC], a1[NSEC], a2[NSEC];
#pragma unroll
        for (int i = 0; i < NSEC; ++i) {
            b0[i] = (double)sos[i * 6 + 0];
            b1[i] = (double)sos[i * 6 + 1];
            b2[i] = (double)sos[i * 6 + 2];
            a1[i] = (double)sos[i * 6 + 4];
            a2[i] = (double)sos[i * 6 + 5];
        }
        double w1[NSEC], w2[NSEC];
#pragma unroll
        for (int i = 0; i < NSEC; ++i) {
            w1[i] = (tid == 2 * i) ? 1.0 : 0.0;
            w2[i] = (tid == 2 * i + 1) ? 1.0 : 0.0;
        }
        double cur = 0.0;   // zero input: unit-state probe, one step
#pragma unroll
        for (int i = 0; i < NSEC; ++i) {
            double y = fma(b0[i], cur, w1[i]);
            double nw1 = fma(b1[i], cur, fma(-a1[i], y, w2[i]));
            double nw2 = fma(b2[i], cur, -(a2[i] * y));
            w1[i] = nw1; w2[i] = nw2; cur = y;
        }
#pragma unroll
        for (int i = 0; i < NSEC; ++i) {
            A[(2 * i) * NSTATE + tid]     = w1[i];   // column tid
            A[(2 * i + 1) * NSTATE + tid] = w2[i];
        }
    }
    __syncthreads();

    int r = tid / NSTATE, c = tid % NSTATE;
    for (int it = 1; it <= 13; ++it) {
        double v = 0.0;
        if (tid < NSTATE * NSTATE) {
#pragma unroll
            for (int k = 0; k < NSTATE; ++k)
                v = fma(A[r * NSTATE + k], A[k * NSTATE + c], v);
        }
        __syncthreads();
        if (tid < NSTATE * NSTATE) {
            A[r * NSTATE + c] = v;
            if (it >= 7) g_Mp[(it - 7) * (NSTATE * NSTATE) + tid] = (float)v;
        }
        __syncthreads();
    }
}

// ---------------------------------------------------------------------------
// One workgroup (128 threads) per signal:
//   1) thread k: zero-state filter of block k -> end state b_k (regs)
//   2) Hillis-Steele scan over blocks: c_k = sum_j M^(k-j) b_j  (7 rounds)
//   3) s_in(k) = c_{k-1};  refilter block k seeded with s_in, write y
// ---------------------------------------------------------------------------
__global__ void __launch_bounds__(K_BLK) k_main(const float* __restrict__ x,
                                                const float* __restrict__ sos,
                                                float* __restrict__ y) {
    __shared__ float Mp[NPOW][NSTATE * NSTATE];
    __shared__ float cbuf[K_BLK][NSTATE + 1];   // pad->13, gcd(13,32)=1
    int sig = blockIdx.x;
    int k = threadIdx.x;

    for (int i = k; i < NPOW * NSTATE * NSTATE; i += K_BLK)
        Mp[i / (NSTATE * NSTATE)][i % (NSTATE * NSTATE)] = g_Mp[i];

    float b0[NSEC], b1[NSEC], b2[NSEC], a1[NSEC], a2[NSEC];
#pragma unroll
    for (int i = 0; i < NSEC; ++i) {
        b0[i] = sos[i * 6 + 0];
        b1[i] = sos[i * 6 + 1];
        b2[i] = sos[i * 6 + 2];
        a1[i] = sos[i * 6 + 4];
        a2[i] = sos[i * 6 + 5];
    }

    const float* xp = x + (size_t)sig * T_LEN + (size_t)k * L_BLK;

    // ---- pass A: zero-state filter, keep only end state ----
    float w1[NSEC], w2[NSEC];
#pragma unroll
    for (int i = 0; i < NSEC; ++i) { w1[i] = 0.f; w2[i] = 0.f; }
#pragma unroll 2
    for (int t = 0; t < L_BLK; t += 4) {
        float4 v = *reinterpret_cast<const float4*>(xp + t);
        float in4[4] = {v.x, v.y, v.z, v.w};
#pragma unroll
        for (int q = 0; q < 4; ++q) {
            float cur = in4[q];
#pragma unroll
            for (int i = 0; i < NSEC; ++i) {
                float yv = fmaf(b0[i], cur, w1[i]);
                w1[i] = fmaf(b1[i], cur, fmaf(-a1[i], yv, w2[i]));
                w2[i] = fmaf(b2[i], cur, -(a2[i] * yv));
                cur = yv;
            }
        }
    }
    float c[NSTATE];
#pragma unroll
    for (int i = 0; i < NSEC; ++i) { c[2 * i] = w1[i]; c[2 * i + 1] = w2[i]; }

    __syncthreads();   // Mp loads complete before scan uses them

    // ---- Hillis-Steele decayed inclusive scan ----
#pragma unroll
    for (int rnd = 0; rnd < NPOW; ++rnd) {
        int d = 1 << rnd;
#pragma unroll
        for (int j = 0; j < NSTATE; ++j) cbuf[k][j] = c[j];
        __syncthreads();
        if (k >= d) {
            float prev[NSTATE];
#pragma unroll
            for (int j = 0; j < NSTATE; ++j) prev[j] = cbuf[k - d][j];
            float nc[NSTATE];
#pragma unroll
            for (int r = 0; r < NSTATE; ++r) {
                float acc = c[r];
#pragma unroll
                for (int kk = 0; kk < NSTATE; ++kk)
                    acc = fmaf(Mp[rnd][r * NSTATE + kk], prev[kk], acc);
                nc[r] = acc;
            }
#pragma unroll
            for (int j = 0; j < NSTATE; ++j) c[j] = nc[j];
        }
        __syncthreads();
    }

    // s_in(k) = c_{k-1}
#pragma unroll
    for (int j = 0; j < NSTATE; ++j) cbuf[k][j] = c[j];
    __syncthreads();
#pragma unroll
    for (int i = 0; i < NSEC; ++i) {
        w1[i] = (k == 0) ? 0.f : cbuf[k - 1][2 * i];
        w2[i] = (k == 0) ? 0.f : cbuf[k - 1][2 * i + 1];
    }

    // ---- pass B: filter with true incoming state, write y ----
    float* yp = y + (size_t)sig * T_LEN + (size_t)k * L_BLK;
#pragma unroll 2
    for (int t = 0; t < L_BLK; t += 4) {
        float4 v = *reinterpret_cast<const float4*>(xp + t);
        float in4[4] = {v.x, v.y, v.z, v.w};
        float out4[4];
#pragma unroll
        for (int q = 0; q < 4; ++q) {
            float cur = in4[q];
#pragma unroll
            for (int i = 0; i < NSEC; ++i) {
                float yv = fmaf(b0[i], cur, w1[i]);
                w1[i] = fmaf(b1[i], cur, fmaf(-a1[i], yv, w2[i]));
                w2[i] = fmaf(b2[i], cur, -(a2[i] * yv));
                cur = yv;
            }
            out4[q] = cur;
        }
        *reinterpret_cast<float4*>(yp + t) = make_float4(out4[0], out4[1], out4[2], out4[3]);
    }
}

extern "C" void kernel_launch(void* const* d_in, const int* in_sizes, int n_in,
                              void* d_out, int out_size, void* d_ws, size_t ws_size,
                              hipStream_t stream) {
    const float* x   = (const float*)d_in[0];
    const float* sos = (const float*)d_in[1];
    if (n_in >= 2 && in_sizes[0] <= 256 && in_sizes[1] > 256) {  // insurance
        x = (const float*)d_in[1];
        sos = (const float*)d_in[0];
    }
    float* out = (float*)d_out;

    int NS = out_size / T_LEN;      // 2048 signals
    if (NS > NS_TOT) NS = NS_TOT;
    if (NS < 1) NS = 1;

    k_matpow<<<1, 256, 0, stream>>>(sos);
    k_main<<<NS, K_BLK, 0, stream>>>(x, sos, out);
}

// Round 5
// 122.080 us; speedup vs baseline: 9.7858x; 1.2888x over previous
//
#include <hip/hip_runtime.h>

#define T_LEN 16384
#define L_BLK 64
#define K_BLK (T_LEN / L_BLK)   // 256 blocks per signal = threads per workgroup
#define NSEC 6                   // order-5 butter = 3 SOS sections; hp+lp = 6
#define NSTATE (2 * NSEC)        // 12 state vars
#define NPOW 8                   // M^(2^i), i=0..7  (M = A^64)
#define NS_TOT 2048
#define NMAT (NSTATE * NSTATE)   // 144

// M powers: g_Mp[i] = (A^64)^(2^i), fp32, built in fp64.
__device__ float g_Mp[NPOW * NMAT];

// ---------------------------------------------------------------------------
// Build A (one-step transition, zero input) in fp64; square 13 times.
// After it squarings A = A0^(2^it); for it=6..13 store as M^(2^(it-6)).
// ---------------------------------------------------------------------------
__global__ void k_matpow(const float* __restrict__ sos) {
    __shared__ double A[NMAT];
    int tid = threadIdx.x;

    if (tid < NSTATE) {
        double b0[NSEC], b1[NSEC], b2[NSEC], a1[NSEC], a2[NSEC];
#pragma unroll
        for (int i = 0; i < NSEC; ++i) {
            b0[i] = (double)sos[i * 6 + 0];
            b1[i] = (double)sos[i * 6 + 1];
            b2[i] = (double)sos[i * 6 + 2];
            a1[i] = (double)sos[i * 6 + 4];
            a2[i] = (double)sos[i * 6 + 5];
        }
        double w1[NSEC], w2[NSEC];
#pragma unroll
        for (int i = 0; i < NSEC; ++i) {
            w1[i] = (tid == 2 * i) ? 1.0 : 0.0;
            w2[i] = (tid == 2 * i + 1) ? 1.0 : 0.0;
        }
        double cur = 0.0;   // zero input: unit-state probe, one step
#pragma unroll
        for (int i = 0; i < NSEC; ++i) {
            double y = fma(b0[i], cur, w1[i]);
            double nw1 = fma(b1[i], cur, fma(-a1[i], y, w2[i]));
            double nw2 = fma(b2[i], cur, -(a2[i] * y));
            w1[i] = nw1; w2[i] = nw2; cur = y;
        }
#pragma unroll
        for (int i = 0; i < NSEC; ++i) {
            A[(2 * i) * NSTATE + tid]     = w1[i];   // column tid
            A[(2 * i + 1) * NSTATE + tid] = w2[i];
        }
    }
    __syncthreads();

    int r = tid / NSTATE, c = tid % NSTATE;
    for (int it = 1; it <= 13; ++it) {
        double v = 0.0;
        if (tid < NMAT) {
#pragma unroll
            for (int k = 0; k < NSTATE; ++k)
                v = fma(A[r * NSTATE + k], A[k * NSTATE + c], v);
        }
        __syncthreads();
        if (tid < NMAT) {
            A[r * NSTATE + c] = v;
            if (it >= 6) g_Mp[(it - 6) * NMAT + tid] = (float)v;
        }
        __syncthreads();
    }
}

// ---------------------------------------------------------------------------
// One workgroup (256 threads) per signal:
//   1) thread k: zero-state filter of 64-sample block k, x stashed in VGPRs
//   2) Hillis-Steele decayed scan over 256 blocks (8 rounds)
//   3) s_in(k) = c_{k-1}; refilter from the stash, write y. x read ONCE.
// ---------------------------------------------------------------------------
__global__ void __launch_bounds__(K_BLK, 4) k_main(const float* __restrict__ x,
                                                   const float* __restrict__ sos,
                                                   float* __restrict__ y) {
    __shared__ float Mp[NPOW][NMAT];
    __shared__ float cbuf[K_BLK][NSTATE + 1];   // pad->13, gcd(13,32)=1
    int sig = blockIdx.x;
    int k = threadIdx.x;

    for (int i = k; i < NPOW * NMAT; i += K_BLK)
        Mp[i / NMAT][i % NMAT] = g_Mp[i];

    float b0[NSEC], b1[NSEC], b2[NSEC], a1[NSEC], a2[NSEC];
#pragma unroll
    for (int i = 0; i < NSEC; ++i) {
        b0[i] = sos[i * 6 + 0];
        b1[i] = sos[i * 6 + 1];
        b2[i] = sos[i * 6 + 2];
        a1[i] = sos[i * 6 + 4];
        a2[i] = sos[i * 6 + 5];
    }

    const float* xp = x + (size_t)sig * T_LEN + (size_t)k * L_BLK;

    // ---- pass A: zero-state filter; stash x in registers (static indexing) ----
    float4 stash[L_BLK / 4];
    float w1[NSEC], w2[NSEC];
#pragma unroll
    for (int i = 0; i < NSEC; ++i) { w1[i] = 0.f; w2[i] = 0.f; }
#pragma unroll
    for (int t4 = 0; t4 < L_BLK / 4; ++t4) {
        float4 v = *reinterpret_cast<const float4*>(xp + 4 * t4);
        stash[t4] = v;
        float in4[4] = {v.x, v.y, v.z, v.w};
#pragma unroll
        for (int q = 0; q < 4; ++q) {
            float cur = in4[q];
#pragma unroll
            for (int i = 0; i < NSEC; ++i) {
                float yv = fmaf(b0[i], cur, w1[i]);
                w1[i] = fmaf(b1[i], cur, fmaf(-a1[i], yv, w2[i]));
                w2[i] = fmaf(b2[i], cur, -(a2[i] * yv));
                cur = yv;
            }
        }
    }
    float c[NSTATE];
#pragma unroll
    for (int i = 0; i < NSEC; ++i) { c[2 * i] = w1[i]; c[2 * i + 1] = w2[i]; }

    __syncthreads();   // Mp loads complete before scan uses them

    // ---- Hillis-Steele decayed inclusive scan: c_k = sum_j M^(k-j) b_j ----
#pragma unroll
    for (int rnd = 0; rnd < NPOW; ++rnd) {
        int d = 1 << rnd;
#pragma unroll
        for (int j = 0; j < NSTATE; ++j) cbuf[k][j] = c[j];
        __syncthreads();
        if (k >= d) {
            float prev[NSTATE];
#pragma unroll
            for (int j = 0; j < NSTATE; ++j) prev[j] = cbuf[k - d][j];
            float nc[NSTATE];
#pragma unroll
            for (int r = 0; r < NSTATE; ++r) {
                float acc = c[r];
#pragma unroll
                for (int kk = 0; kk < NSTATE; ++kk)
                    acc = fmaf(Mp[rnd][r * NSTATE + kk], prev[kk], acc);
                nc[r] = acc;
            }
#pragma unroll
            for (int j = 0; j < NSTATE; ++j) c[j] = nc[j];
        }
        __syncthreads();
    }

    // s_in(k) = c_{k-1}  (state after block k-1)
#pragma unroll
    for (int j = 0; j < NSTATE; ++j) cbuf[k][j] = c[j];
    __syncthreads();
#pragma unroll
    for (int i = 0; i < NSEC; ++i) {
        w1[i] = (k == 0) ? 0.f : cbuf[k - 1][2 * i];
        w2[i] = (k == 0) ? 0.f : cbuf[k - 1][2 * i + 1];
    }

    // ---- pass B: filter from stash with true incoming state, write y ----
    float* yp = y + (size_t)sig * T_LEN + (size_t)k * L_BLK;
#pragma unroll
    for (int t4 = 0; t4 < L_BLK / 4; ++t4) {
        float4 v = stash[t4];
        float in4[4] = {v.x, v.y, v.z, v.w};
        float out4[4];
#pragma unroll
        for (int q = 0; q < 4; ++q) {
            float cur = in4[q];
#pragma unroll
            for (int i = 0; i < NSEC; ++i) {
                float yv = fmaf(b0[i], cur, w1[i]);
                w1[i] = fmaf(b1[i], cur, fmaf(-a1[i], yv, w2[i]));
                w2[i] = fmaf(b2[i], cur, -(a2[i] * yv));
                cur = yv;
            }
            out4[q] = cur;
        }
        *reinterpret_cast<float4*>(yp + 4 * t4) = make_float4(out4[0], out4[1], out4[2], out4[3]);
    }
}

extern "C" void kernel_launch(void* const* d_in, const int* in_sizes, int n_in,
                              void* d_out, int out_size, void* d_ws, size_t ws_size,
                              hipStream_t stream) {
    const float* x   = (const float*)d_in[0];
    const float* sos = (const float*)d_in[1];
    if (n_in >= 2 && in_sizes[0] <= 256 && in_sizes[1] > 256) {  // insurance
        x = (const float*)d_in[1];
        sos = (const float*)d_in[0];
    }
    float* out = (float*)d_out;

    int NS = out_size / T_LEN;      // 2048 signals
    if (NS > NS_TOT) NS = NS_TOT;
    if (NS < 1) NS = 1;

    k_matpow<<<1, 256, 0, stream>>>(sos);
    k_main<<<NS, K_BLK, 0, stream>>>(x, sos, out);
}

// Round 6
// 118.366 us; speedup vs baseline: 10.0928x; 1.0314x over previous
//
#include <hip/hip_runtime.h>

#define T_LEN 16384
#define NSEC 6                   // order-5 butter = 3 SOS each for hp+lp
#define NSTATE 12
#define NMAT (NSTATE * NSTATE)   // 144
#define NPOW 8                   // M^(2^i), i=0..7, M = A^64
#define NTHR 512                 // 2 signals x 256 scan-threads
#define NS_TOT 2048

__device__ __forceinline__ float rfl(float v) {
    return __int_as_float(__builtin_amdgcn_readfirstlane(__float_as_int(v)));
}
// XOR swizzle in float4 units: chunk-linear f4 index -> conflict-free LDS slot
__device__ __forceinline__ int swz(int f) {
    return (f & ~15) | ((f ^ (f >> 4)) & 15);
}

__global__ void __launch_bounds__(NTHR, 4)
k_main(const float* __restrict__ x, const float* __restrict__ sos,
       float* __restrict__ y) {
    __shared__ float  Mp[NPOW][NMAT];   // fp32 scan matrices
    __shared__ double Ad[NMAT];         // fp64 squaring workspace
    __shared__ float4 sm4[1664];        // stage (1024 f4) aliased with cbuf (512*13 f)
    float* cb = (float*)sm4;

    const int k = threadIdx.x;
    const int t = k & 255;              // position within signal's scan
    const int h = k >> 8;               // which signal of the pair
    const int sig0 = blockIdx.x * 2;

    // ---- coefficients (wave-uniform) -> SGPRs ----
    float b0[NSEC], b1[NSEC], b2[NSEC], a1[NSEC], a2[NSEC];
#pragma unroll
    for (int i = 0; i < NSEC; ++i) {
        b0[i] = rfl(sos[i * 6 + 0]);
        b1[i] = rfl(sos[i * 6 + 1]);
        b2[i] = rfl(sos[i * 6 + 2]);
        a1[i] = rfl(sos[i * 6 + 4]);
        a2[i] = rfl(sos[i * 6 + 5]);
    }

    // ---- build one-step transition A (column k = unit-state probe) ----
    if (k < NSTATE) {
        float w1[NSEC], w2[NSEC];
#pragma unroll
        for (int i = 0; i < NSEC; ++i) {
            w1[i] = (k == 2 * i) ? 1.f : 0.f;
            w2[i] = (k == 2 * i + 1) ? 1.f : 0.f;
        }
        float cur = 0.f;   // zero input
#pragma unroll
        for (int i = 0; i < NSEC; ++i) {
            float yv = fmaf(b0[i], cur, w1[i]);
            float n1 = fmaf(b1[i], cur, fmaf(-a1[i], yv, w2[i]));
            float n2 = fmaf(b2[i], cur, -(a2[i] * yv));
            w1[i] = n1; w2[i] = n2; cur = yv;
        }
#pragma unroll
        for (int i = 0; i < NSEC; ++i) {
            Ad[(2 * i) * NSTATE + k]     = (double)w1[i];
            Ad[(2 * i + 1) * NSTATE + k] = (double)w2[i];
        }
    }
    __syncthreads();
    // ---- 13 fp64 squarings: after it, Ad = A^(2^it); store Mp for it>=6 ----
    {
        const int rr = k / NSTATE, cc = k % NSTATE;
        for (int it = 1; it <= 13; ++it) {
            double v = 0.0;
            if (k < NMAT) {
#pragma unroll
                for (int kk = 0; kk < NSTATE; ++kk)
                    v = fma(Ad[rr * NSTATE + kk], Ad[kk * NSTATE + cc], v);
            }
            __syncthreads();
            if (k < NMAT) {
                Ad[rr * NSTATE + cc] = v;
                if (it >= 6) Mp[it - 6][k] = (float)v;
            }
            __syncthreads();
        }
    }

    // ---- read staging: 8 chunks of 4096 floats, coalesced -> swizzled LDS ----
    float4 stash[16];
#pragma unroll 1
    for (int r = 0; r < 8; ++r) {
        const int hr = r >> 2, c = r & 3;
        const float4* src = (const float4*)(x + (size_t)(sig0 + hr) * T_LEN + (c << 12));
        float4 v0 = src[k];
        float4 v1 = src[k + 512];
        __syncthreads();                 // prev round's owner reads done
        sm4[swz(k)]       = v0;
        sm4[swz(k + 512)] = v1;
        __syncthreads();
        if (h == hr && (t >> 6) == c) {  // 64 consecutive threads = one wave
            const int tp = t & 63;
#pragma unroll
            for (int m = 0; m < 16; ++m)
                stash[m] = sm4[tp * 16 + (m ^ (tp & 15))];
        }
    }

    // ---- pass A: zero-state filter over stash, keep end state ----
    float w1_[NSEC], w2_[NSEC];
#pragma unroll
    for (int i = 0; i < NSEC; ++i) { w1_[i] = 0.f; w2_[i] = 0.f; }

    auto fstep = [&](float cur) -> float {
#pragma unroll
        for (int i = 0; i < NSEC; ++i) {
            float yv = fmaf(b0[i], cur, w1_[i]);
            w1_[i] = fmaf(b1[i], cur, fmaf(-a1[i], yv, w2_[i]));
            w2_[i] = fmaf(b2[i], cur, -(a2[i] * yv));
            cur = yv;
        }
        return cur;
    };

#pragma unroll
    for (int m = 0; m < 16; ++m) {
        float4 v = stash[m];
        fstep(v.x); fstep(v.y); fstep(v.z); fstep(v.w);
    }
    float c0[NSTATE];
#pragma unroll
    for (int i = 0; i < NSEC; ++i) { c0[2 * i] = w1_[i]; c0[2 * i + 1] = w2_[i]; }

    // ---- Hillis-Steele decayed scan over 256-thread segments ----
    __syncthreads();                     // owner reads done; cb region free
#pragma unroll 1
    for (int rnd = 0; rnd < NPOW; ++rnd) {
        const int d = 1 << rnd;
#pragma unroll
        for (int j = 0; j < NSTATE; ++j) cb[k * 13 + j] = c0[j];
        __syncthreads();
        if (t >= d) {
            float pr[NSTATE], nc[NSTATE];
#pragma unroll
            for (int j = 0; j < NSTATE; ++j) pr[j] = cb[(k - d) * 13 + j];
#pragma unroll
            for (int q = 0; q < NSTATE; ++q) {
                float acc = c0[q];
#pragma unroll
                for (int kk = 0; kk < NSTATE; ++kk)
                    acc = fmaf(Mp[rnd][q * NSTATE + kk], pr[kk], acc);
                nc[q] = acc;
            }
#pragma unroll
            for (int j = 0; j < NSTATE; ++j) c0[j] = nc[j];
        }
        __syncthreads();
    }
    // seed state for block t = c_{t-1}
#pragma unroll
    for (int j = 0; j < NSTATE; ++j) cb[k * 13 + j] = c0[j];
    __syncthreads();
#pragma unroll
    for (int i = 0; i < NSEC; ++i) {
        w1_[i] = (t == 0) ? 0.f : cb[(k - 1) * 13 + 2 * i];
        w2_[i] = (t == 0) ? 0.f : cb[(k - 1) * 13 + 2 * i + 1];
    }

    // ---- pass B: refilter stash in place with true incoming state ----
#pragma unroll
    for (int m = 0; m < 16; ++m) {
        float4 v = stash[m];
        v.x = fstep(v.x); v.y = fstep(v.y); v.z = fstep(v.z); v.w = fstep(v.w);
        stash[m] = v;
    }

    // ---- write staging: swizzled LDS -> coalesced global stores ----
#pragma unroll 1
    for (int r = 0; r < 8; ++r) {
        const int hr = r >> 2, c = r & 3;
        __syncthreads();                 // prev round's consumer reads done
        if (h == hr && (t >> 6) == c) {
            const int tp = t & 63;
#pragma unroll
            for (int m = 0; m < 16; ++m)
                sm4[tp * 16 + (m ^ (tp & 15))] = stash[m];
        }
        __syncthreads();
        float4* dst = (float4*)(y + (size_t)(sig0 + hr) * T_LEN + (c << 12));
        dst[k]       = sm4[swz(k)];
        dst[k + 512] = sm4[swz(k + 512)];
    }
}

extern "C" void kernel_launch(void* const* d_in, const int* in_sizes, int n_in,
                              void* d_out, int out_size, void* d_ws, size_t ws_size,
                              hipStream_t stream) {
    const float* x   = (const float*)d_in[0];
    const float* sos = (const float*)d_in[1];
    if (n_in >= 2 && in_sizes[0] <= 256 && in_sizes[1] > 256) {  // insurance
        x = (const float*)d_in[1];
        sos = (const float*)d_in[0];
    }
    float* out = (float*)d_out;

    int NS = out_size / T_LEN;      // 2048 signals
    if (NS > NS_TOT) NS = NS_TOT;
    if (NS < 2) NS = 2;

    k_main<<<NS / 2, NTHR, 0, stream>>>(x, sos, out);
}

// Round 7
// 107.556 us; speedup vs baseline: 11.1072x; 1.1005x over previous
//
#include <hip/hip_runtime.h>

#define T_LEN 16384
#define NSEC 6                   // order-5 butter = 3 SOS each (hp+lp)
#define NSTATE 12
#define NMAT (NSTATE * NSTATE)   // 144
#define NPOW 6                   // M^(2^i), i=0..5, M = A^64 (M^32 max needed)
#define NTHR 256                 // 1 signal per block; 4 waves
#define NS_TOT 2048

// (A^64)^(2^i), i=0..5, fp32 (built in fp64 by k_matpow).
__device__ float g_Mp[NPOW * NMAT];

__device__ __forceinline__ float rfl(float v) {
    return __int_as_float(__builtin_amdgcn_readfirstlane(__float_as_int(v)));
}

// ---------------------------------------------------------------------------
// Build one-step transition A (fp64), square 11 times; store A^(2^it), it=6..11
// as M^(2^(it-6)) = (A^64)^(2^i), i=0..5.
// ---------------------------------------------------------------------------
__global__ void k_matpow(const float* __restrict__ sos) {
    __shared__ double A[NMAT];
    int tid = threadIdx.x;

    if (tid < NSTATE) {
        double b0[NSEC], b1[NSEC], b2[NSEC], a1[NSEC], a2[NSEC];
#pragma unroll
        for (int i = 0; i < NSEC; ++i) {
            b0[i] = (double)sos[i * 6 + 0];
            b1[i] = (double)sos[i * 6 + 1];
            b2[i] = (double)sos[i * 6 + 2];
            a1[i] = (double)sos[i * 6 + 4];
            a2[i] = (double)sos[i * 6 + 5];
        }
        double w1[NSEC], w2[NSEC];
#pragma unroll
        for (int i = 0; i < NSEC; ++i) {
            w1[i] = (tid == 2 * i) ? 1.0 : 0.0;
            w2[i] = (tid == 2 * i + 1) ? 1.0 : 0.0;
        }
        double cur = 0.0;   // zero input: unit-state probe, one step
#pragma unroll
        for (int i = 0; i < NSEC; ++i) {
            double yv = fma(b0[i], cur, w1[i]);
            double n1 = fma(b1[i], cur, fma(-a1[i], yv, w2[i]));
            double n2 = fma(b2[i], cur, -(a2[i] * yv));
            w1[i] = n1; w2[i] = n2; cur = yv;
        }
#pragma unroll
        for (int i = 0; i < NSEC; ++i) {
            A[(2 * i) * NSTATE + tid]     = w1[i];   // column tid
            A[(2 * i + 1) * NSTATE + tid] = w2[i];
        }
    }
    __syncthreads();
    const int rr = tid / NSTATE, cc = tid % NSTATE;
    for (int it = 1; it <= 11; ++it) {
        double v = 0.0;
        if (tid < NMAT) {
#pragma unroll
            for (int kk = 0; kk < NSTATE; ++kk)
                v = fma(A[rr * NSTATE + kk], A[kk * NSTATE + cc], v);
        }
        __syncthreads();
        if (tid < NMAT) {
            A[rr * NSTATE + cc] = v;
            if (it >= 6) g_Mp[(it - 6) * NMAT + tid] = (float)v;
        }
        __syncthreads();
    }
}

// ---------------------------------------------------------------------------
// One 256-thread block per signal. Thread t owns samples [t*64, t*64+64).
//   passA: zero-state filter (x stashed in 16 float4 regs) -> end state c
//   scan : 6-round wave-local shuffle scan (exact within wave); one barrier
//          cross-wave fix via M^(lane+1)*c63_prev (decay makes wave-2+ ~ 0)
//   passB: refilter stash with true seed state
//   write: per-wave 16KB swizzled LDS staging -> coalesced global stores
// ---------------------------------------------------------------------------
__global__ void __launch_bounds__(NTHR, 4)
k_main(const float* __restrict__ x, const float* __restrict__ sos,
       float* __restrict__ y) {
    __shared__ float Mp[NPOW][NMAT];
    __shared__ float cw[4][NSTATE];      // per-wave c at lane 63
    __shared__ float4 sm4[1024];         // 16KB write-stage buffer

    const int k = threadIdx.x;
    const int lane = k & 63;
    const int w = k >> 6;                // wave id 0..3
    const int sig = blockIdx.x;

    // stage scan matrices (loads overlap pass A; barrier before scan)
    for (int i = k; i < NPOW * NMAT; i += NTHR)
        Mp[i / NMAT][i % NMAT] = g_Mp[i];

    // coefficients -> SGPRs
    float b0[NSEC], b1[NSEC], b2[NSEC], a1[NSEC], a2[NSEC];
#pragma unroll
    for (int i = 0; i < NSEC; ++i) {
        b0[i] = rfl(sos[i * 6 + 0]);
        b1[i] = rfl(sos[i * 6 + 1]);
        b2[i] = rfl(sos[i * 6 + 2]);
        a1[i] = rfl(sos[i * 6 + 4]);
        a2[i] = rfl(sos[i * 6 + 5]);
    }

    // ---- load 64 samples into registers; pass A (zero state) ----
    const float4* xp4 = (const float4*)(x + (size_t)sig * T_LEN) + k * 16;
    float4 stash[16];
    float w1_[NSEC], w2_[NSEC];
#pragma unroll
    for (int i = 0; i < NSEC; ++i) { w1_[i] = 0.f; w2_[i] = 0.f; }

    auto fstep = [&](float cur) -> float {
#pragma unroll
        for (int i = 0; i < NSEC; ++i) {
            float yv = fmaf(b0[i], cur, w1_[i]);
            w1_[i] = fmaf(b1[i], cur, fmaf(-a1[i], yv, w2_[i]));
            w2_[i] = fmaf(b2[i], cur, -(a2[i] * yv));
            cur = yv;
        }
        return cur;
    };

#pragma unroll
    for (int m = 0; m < 16; ++m) {
        float4 v = xp4[m];
        stash[m] = v;
        fstep(v.x); fstep(v.y); fstep(v.z); fstep(v.w);
    }
    float c0[NSTATE];
#pragma unroll
    for (int i = 0; i < NSEC; ++i) { c0[2 * i] = w1_[i]; c0[2 * i + 1] = w2_[i]; }

    __syncthreads();   // Mp staged

    // ---- wave-local inclusive scan: 6 shuffle rounds, no barriers ----
#pragma unroll
    for (int rnd = 0; rnd < 6; ++rnd) {
        const int d = 1 << rnd;
        float pr[NSTATE];
#pragma unroll
        for (int j = 0; j < NSTATE; ++j) pr[j] = __shfl_up(c0[j], d, 64);
        if (lane >= d) {
            float nc[NSTATE];
#pragma unroll
            for (int q = 0; q < NSTATE; ++q) {
                float acc = c0[q];
#pragma unroll
                for (int kk = 0; kk < NSTATE; ++kk)
                    acc = fmaf(Mp[rnd][q * NSTATE + kk], pr[kk], acc);
                nc[q] = acc;
            }
#pragma unroll
            for (int j = 0; j < NSTATE; ++j) c0[j] = nc[j];
        }
    }

    // wave totals for cross-wave correction
    if (lane == 63) {
#pragma unroll
        for (int j = 0; j < NSTATE; ++j) cw[w][j] = c0[j];
    }
    __syncthreads();

    // ---- cross-wave correction: c += M^(lane+1) * c63_prev  (waves 1..3) ----
    if (w > 0) {
        float v[NSTATE];
#pragma unroll
        for (int j = 0; j < NSTATE; ++j) v[j] = cw[w - 1][j];
#pragma unroll
        for (int i = 0; i < NPOW; ++i) {
            if (((lane + 1) >> i) & 1) {
                float nv[NSTATE];
#pragma unroll
                for (int q = 0; q < NSTATE; ++q) {
                    float acc = 0.f;
#pragma unroll
                    for (int kk = 0; kk < NSTATE; ++kk)
                        acc = fmaf(Mp[i][q * NSTATE + kk], v[kk], acc);
                    nv[q] = acc;
                }
#pragma unroll
                for (int j = 0; j < NSTATE; ++j) v[j] = nv[j];
            }
        }
        if (lane != 63) {   // lane 63 would need M^64 ~ 1e-14: drop
#pragma unroll
            for (int j = 0; j < NSTATE; ++j) c0[j] += v[j];
        }
    }

    // ---- seed state s_in(k) = c_{k-1} ----
    float si[NSTATE];
#pragma unroll
    for (int j = 0; j < NSTATE; ++j) si[j] = __shfl_up(c0[j], 1, 64);
    if (lane == 0) {
#pragma unroll
        for (int j = 0; j < NSTATE; ++j) si[j] = (w == 0) ? 0.f : cw[w - 1][j];
    }
#pragma unroll
    for (int i = 0; i < NSEC; ++i) { w1_[i] = si[2 * i]; w2_[i] = si[2 * i + 1]; }

    // ---- pass B: refilter stash with true incoming state ----
#pragma unroll
    for (int m = 0; m < 16; ++m) {
        float4 v = stash[m];
        v.x = fstep(v.x); v.y = fstep(v.y); v.z = fstep(v.z); v.w = fstep(v.w);
        stash[m] = v;
    }

    // ---- write staging: one wave's 16KB per round, swizzled, coalesced out ----
    float4* yp4 = (float4*)(y + (size_t)sig * T_LEN);
#pragma unroll 1
    for (int r = 0; r < 4; ++r) {
        if (w == r) {
#pragma unroll
            for (int m = 0; m < 16; ++m)
                sm4[lane * 16 + (m ^ (lane & 15))] = stash[m];
        }
        __syncthreads();
#pragma unroll
        for (int q = 0; q < 4; ++q) {
            int j = k + 256 * q;                       // 0..1023
            int s = (j & ~15) | ((j ^ (j >> 4)) & 15); // matches writer swizzle
            yp4[r * 1024 + j] = sm4[s];
        }
        if (r < 3) __syncthreads();
    }
}

extern "C" void kernel_launch(void* const* d_in, const int* in_sizes, int n_in,
                              void* d_out, int out_size, void* d_ws, size_t ws_size,
                              hipStream_t stream) {
    const float* x   = (const float*)d_in[0];
    const float* sos = (const float*)d_in[1];
    if (n_in >= 2 && in_sizes[0] <= 256 && in_sizes[1] > 256) {  // insurance
        x = (const float*)d_in[1];
        sos = (const float*)d_in[0];
    }
    float* out = (float*)d_out;

    int NS = out_size / T_LEN;      // 2048 signals
    if (NS > NS_TOT) NS = NS_TOT;
    if (NS < 1) NS = 1;

    k_matpow<<<1, 256, 0, stream>>>(sos);
    k_main<<<NS, NTHR, 0, stream>>>(x, sos, out);
}